// Round 1
// baseline (1734.591 us; speedup 1.0000x reference)
//
#include <hip/hip_runtime.h>
#include <hip/hip_bf16.h>
#include <cstdint>
#include <cstddef>

#define N_NODES 4096
#define E_EDGES 16384
#define D_IN 256
#define D_OUT 256

typedef __attribute__((ext_vector_type(4))) float f32x4;
typedef __attribute__((ext_vector_type(8))) short s16x8;

__device__ __forceinline__ short f2bf(float x) {
    uint32_t u = __builtin_bit_cast(uint32_t, x);
    u += 0x7fffu + ((u >> 16) & 1u);   // round-to-nearest-even
    return (short)(u >> 16);
}

// ---------------- s[e] = edge_features[e,:] . p ----------------
__global__ __launch_bounds__(256) void k_edge_scalar(
    const float* __restrict__ ef, const float* __restrict__ p,
    float* __restrict__ s)
{
    int e = blockIdx.x * 256 + threadIdx.x;
    if (e < E_EDGES) {
        s[e] = ef[3 * e] * p[0] + ef[3 * e + 1] * p[1] + ef[3 * e + 2] * p[2];
    }
}

// ---------------- A = bf16(T * s), B = bf16(T) ----------------
__global__ __launch_bounds__(256) void k_prep_ab(
    const float* __restrict__ T, const float* __restrict__ s,
    s16x8* __restrict__ A, s16x8* __restrict__ B)
{
    const size_t total8 = (size_t)N_NODES * E_EDGES / 8;
    size_t i = (size_t)blockIdx.x * blockDim.x + threadIdx.x;
    const size_t stride = (size_t)gridDim.x * blockDim.x;
    for (; i < total8; i += stride) {
        const size_t base = i * 8;
        const int e = (int)(base & (size_t)(E_EDGES - 1));
        const f32x4* t4 = (const f32x4*)(T + base);
        const f32x4 t0 = t4[0], t1 = t4[1];
        const f32x4 s0 = *(const f32x4*)(s + e);
        const f32x4 s1 = *(const f32x4*)(s + e + 4);
        s16x8 a, b;
#pragma unroll
        for (int j = 0; j < 4; ++j) {
            b[j]     = f2bf(t0[j]);
            b[j + 4] = f2bf(t1[j]);
            a[j]     = f2bf(t0[j] * s0[j]);
            a[j + 4] = f2bf(t1[j] * s1[j]);
        }
        A[i] = a;
        B[i] = b;
    }
}

// ---------------- HWt[d][j] = bf16( (H_v @ W)[j][d] ) ----------------
__global__ __launch_bounds__(256) void k_hwt(
    const float* __restrict__ Hv, const float* __restrict__ W,
    short* __restrict__ HWt)
{
    __shared__ float h[D_IN];
    const int r = blockIdx.x;      // node j
    const int d = threadIdx.x;     // output feature
    h[d] = Hv[(size_t)r * D_IN + d];
    __syncthreads();
    float acc = 0.f;
#pragma unroll 8
    for (int k = 0; k < D_IN; ++k)
        acc = fmaf(h[k], W[(size_t)k * D_OUT + d], acc);
    HWt[(size_t)d * N_NODES + r] = f2bf(acc);
}

// ---------------- C = A @ B^T  (m97-style 128x128 tile, bf16 MFMA) ----------
// EPI==0: C' = bf16( ((i==j)?1:C) * adj[i][j] )  -> Cb (bf16)
// EPI==1: C' = C + bias[col]                     -> Cf (f32)
template <int EPI>
__global__ __launch_bounds__(256) void k_gemm_bt(
    const short* __restrict__ A,   // [M][K] bf16 bits, row-major
    const short* __restrict__ B,   // [Nc][K] bf16 bits, row-major
    int M, int Nc, int K,
    const float* __restrict__ adj, short* __restrict__ Cb,
    const float* __restrict__ bias, float* __restrict__ Cf)
{
    __shared__ short As[128 * 32];   // [row][k] 8KB
    __shared__ short Bs[128 * 32];   // [col][k] 8KB

    // XCD-aware swizzle (nwg divisible by 8 in both uses: 1024 and 64)
    const int nbx = gridDim.x;
    const int nwg = gridDim.x * gridDim.y;
    const int lin = blockIdx.y * nbx + blockIdx.x;
    const int swz = (lin & 7) * (nwg >> 3) + (lin >> 3);
    const int bx = swz % nbx;
    const int by = swz / nbx;

    const int tid = threadIdx.x;
    const int wave = tid >> 6;
    const int lane = tid & 63;
    const int row0 = by * 128, col0 = bx * 128;
    const int wm = (wave >> 1) * 64;   // wave row offset in tile
    const int wn = (wave & 1) * 64;    // wave col offset in tile

    f32x4 acc[4][4] = {};

    // staging: pass p (p=0,1) covers tile rows [p*64, p*64+64), each lane 16B
    const int srow = tid >> 2;          // 0..63
    const int scol = (tid & 3) * 8;     // 0,8,16,24 (shorts)
    const short* Ag = A + (size_t)(row0 + srow) * K + scol;
    const short* Bg = B + (size_t)(col0 + srow) * K + scol;
    char* AsB = (char*)As;
    char* BsB = (char*)Bs;
    const unsigned lds0 = wave * 1024;          // wave-uniform LDS base, pass 0
    const unsigned lds1 = 4096 + wave * 1024;   // pass 1

    const int fr = lane & 15;        // row/col within 16x16 fragment
    const int kg = (lane >> 4) * 8;  // k-slice

    for (int k0 = 0; k0 < K; k0 += 32) {
        __builtin_amdgcn_global_load_lds(
            (const __attribute__((address_space(1))) void*)(Ag + k0),
            (__attribute__((address_space(3))) void*)(AsB + lds0), 16, 0, 0);
        __builtin_amdgcn_global_load_lds(
            (const __attribute__((address_space(1))) void*)(Ag + (size_t)64 * K + k0),
            (__attribute__((address_space(3))) void*)(AsB + lds1), 16, 0, 0);
        __builtin_amdgcn_global_load_lds(
            (const __attribute__((address_space(1))) void*)(Bg + k0),
            (__attribute__((address_space(3))) void*)(BsB + lds0), 16, 0, 0);
        __builtin_amdgcn_global_load_lds(
            (const __attribute__((address_space(1))) void*)(Bg + (size_t)64 * K + k0),
            (__attribute__((address_space(3))) void*)(BsB + lds1), 16, 0, 0);
        __syncthreads();   // compiler drains vmcnt(0) before s_barrier

        s16x8 af[4], bfr[4];
#pragma unroll
        for (int m = 0; m < 4; ++m)
            af[m] = *(const s16x8*)&As[(wm + m * 16 + fr) * 32 + kg];
#pragma unroll
        for (int n = 0; n < 4; ++n)
            bfr[n] = *(const s16x8*)&Bs[(wn + n * 16 + fr) * 32 + kg];
#pragma unroll
        for (int m = 0; m < 4; ++m)
#pragma unroll
            for (int n = 0; n < 4; ++n)
                acc[m][n] = __builtin_amdgcn_mfma_f32_16x16x32_bf16(
                    af[m], bfr[n], acc[m][n], 0, 0, 0);
        __syncthreads();
    }

    // epilogue: C/D layout col=lane&15, row=(lane>>4)*4+r  [verified m89/m91]
    const int cr = (lane >> 4) * 4;
    const int cc = lane & 15;
#pragma unroll
    for (int m = 0; m < 4; ++m) {
#pragma unroll
        for (int n = 0; n < 4; ++n) {
#pragma unroll
            for (int r = 0; r < 4; ++r) {
                const int grow = row0 + wm + m * 16 + cr + r;
                const int gcol = col0 + wn + n * 16 + cc;
                const float v = acc[m][n][r];
                if (EPI == 0) {
                    const float mv = (grow == gcol) ? 1.0f : v;
                    Cb[(size_t)grow * Nc + gcol] =
                        f2bf(mv * adj[(size_t)grow * Nc + gcol]);
                } else {
                    Cf[(size_t)grow * Nc + gcol] = v + bias[gcol];
                }
            }
        }
    }
}

extern "C" void kernel_launch(void* const* d_in, const int* in_sizes, int n_in,
                              void* d_out, int out_size, void* d_ws, size_t ws_size,
                              hipStream_t stream)
{
    const float* Hv   = (const float*)d_in[0];  // [N, DIN]
    const float* ef   = (const float*)d_in[1];  // [E, 3]
    const float* adj  = (const float*)d_in[2];  // [N, N]
    const float* T    = (const float*)d_in[3];  // [N, E]
    const float* W    = (const float*)d_in[4];  // [DIN, DOUT]
    const float* bias = (const float*)d_in[5];  // [DOUT]
    const float* p    = (const float*)d_in[6];  // [1, 3]
    float* out = (float*)d_out;                 // [N, DOUT] f32

    char* ws = (char*)d_ws;
    short* Abuf = (short*)ws;                                  // 128 MB: bf16(T*s)
    short* Bbuf = (short*)(ws + (size_t)128 * 1024 * 1024);    // 128 MB: bf16(T)
    short* adjA = (short*)(ws + (size_t)256 * 1024 * 1024);    //  32 MB: bf16 adjusted_A
    short* HWt  = (short*)(ws + (size_t)288 * 1024 * 1024);    //   2 MB: bf16 (Hv@W)^T
    float* sbuf = (float*)(ws + (size_t)291 * 1024 * 1024);    //  64 KB: s

    k_edge_scalar<<<E_EDGES / 256, 256, 0, stream>>>(ef, p, sbuf);
    k_prep_ab<<<2048, 256, 0, stream>>>(T, sbuf, (s16x8*)Abuf, (s16x8*)Bbuf);
    k_hwt<<<N_NODES, 256, 0, stream>>>(Hv, W, HWt);

    dim3 g1(N_NODES / 128, N_NODES / 128);   // 32x32 = 1024 blocks
    k_gemm_bt<0><<<g1, 256, 0, stream>>>(Abuf, Bbuf, N_NODES, N_NODES, E_EDGES,
                                         adj, adjA, nullptr, nullptr);

    dim3 g2(D_OUT / 128, N_NODES / 128);     // 2x32 = 64 blocks
    k_gemm_bt<1><<<g2, 256, 0, stream>>>(adjA, HWt, N_NODES, D_OUT, N_NODES,
                                         nullptr, nullptr, bias, out);
}